// Round 14
// baseline (346.349 us; speedup 1.0000x reference)
//
#include <hip/hip_runtime.h>
#include <hip/hip_bf16.h>

typedef __attribute__((ext_vector_type(8))) short bf16x8;
typedef __attribute__((ext_vector_type(4))) float f32x4;
typedef __attribute__((ext_vector_type(2))) float f32x2;

__device__ __forceinline__ short f2b(float f) {
    unsigned u = __builtin_bit_cast(unsigned, f);
    unsigned r = (u + 0x7FFFu + ((u >> 16) & 1u)) >> 16;
    return (short)r;
}

__device__ __forceinline__ unsigned cvt_pk_bf16(float lo, float hi) {
    unsigned r;
    asm("v_cvt_pk_bf16_f32 %0, %1, %2" : "=v"(r) : "v"(lo), "v"(hi));
    return r;
}

__device__ __forceinline__ float fexp2(float x) {
    float r;
    asm("v_exp_f32 %0, %1" : "=v"(r) : "v"(x));
    return r;
}

__device__ __forceinline__ f32x2 pk_add(f32x2 a, f32x2 b) {
    f32x2 d;
    asm("v_pk_add_f32 %0, %1, %2" : "=v"(d) : "v"(a), "v"(b));
    return d;
}

__device__ __forceinline__ void gload_lds16(const void* g, void* l) {
    __builtin_amdgcn_global_load_lds((const __attribute__((address_space(1))) unsigned*)g,
                                     (__attribute__((address_space(3))) unsigned*)l, 16, 0, 0);
}

// ---------- convert x f32->bf16, k-chunk pre-swizzled (chunk^row&7 within 64-group) ----------
__global__ void conv_swz(const float* __restrict__ in, short* __restrict__ out, long nch) {
    long i = (long)blockIdx.x * blockDim.x + threadIdx.x;
    long stride = (long)gridDim.x * blockDim.x;
    for (; i < nch; i += stride) {
        long m = i >> 7;            // row (K=1024 -> 128 chunks of 8)
        int ch = (int)(i & 127);
        int p = (ch & ~7) | ((ch ^ (int)m) & 7);
        const float4* s = (const float4*)(in + i * 8);
        float4 a = s[0], b = s[1];
        bf16x8 ov;
        ov[0] = f2b(a.x); ov[1] = f2b(a.y); ov[2] = f2b(a.z); ov[3] = f2b(a.w);
        ov[4] = f2b(b.x); ov[5] = f2b(b.y); ov[6] = f2b(b.z); ov[7] = f2b(b.w);
        *(bf16x8*)(out + (m << 10) + p * 8) = ov;
    }
}

// ---------- transpose + convert + k-chunk pre-swizzle: in [R=K][C] f32 -> outT [C][K] bf16 ----------
__global__ void transpose_swz(const float* __restrict__ in, short* __restrict__ outT, int R, int C) {
    __shared__ float t[32][33];
    int c0 = blockIdx.x * 32, r0 = blockIdx.y * 32;
    int tx = threadIdx.x, ty = threadIdx.y; // 32 x 8
    #pragma unroll
    for (int j = 0; j < 4; ++j)
        t[ty + j * 8][tx] = in[(long)(r0 + ty + j * 8) * C + c0 + tx];
    __syncthreads();
    #pragma unroll
    for (int j = 0; j < 4; ++j) {
        int n = c0 + ty + j * 8;    // output row
        int k = r0 + tx;            // k index
        int kp = (k & ~63) | ((((k >> 3) ^ n) & 7) << 3) | (k & 7);
        outT[(long)n * R + kp] = f2b(t[tx][ty + j * 8]);
    }
}

// ---------- v transpose: vrow [bh][li][64] -> vT [bh][64][2048] with j-swizzle ----------
__global__ void vtrans_swz(const short* __restrict__ vrow, short* __restrict__ vT) {
    __shared__ short t[64][66];
    const int bh = blockIdx.x & 63;
    const int li0 = ((blockIdx.x >> 6) & 31) << 6;
    const int tid = threadIdx.x;
    const short* src = vrow + ((long)bh * 2048 + li0) * 64;
    {
        int id0 = tid, id1 = tid + 256;      // 512 16B-chunks: 64 rows x 8 chunks
        int r0 = id0 >> 3, c0 = id0 & 7;
        int r1 = id1 >> 3, c1 = id1 & 7;
        *(bf16x8*)&t[r0][c0 * 8] = *(const bf16x8*)&src[r0 * 64 + c0 * 8];
        *(bf16x8*)&t[r1][c1 * 8] = *(const bf16x8*)&src[r1 * 64 + c1 * 8];
    }
    __syncthreads();
    const int d = tid >> 2, part = tid & 3;  // each thread: row d, li-chunks 2*part, 2*part+1
    short* dst = vT + ((long)bh * 64 + d) * 2048 + li0;
    const int sw = d & 7;
    #pragma unroll
    for (int cc = 0; cc < 2; ++cc) {
        int cl = part * 2 + cc;              // source li-chunk (8 elems)
        bf16x8 val;
        #pragma unroll
        for (int i = 0; i < 8; ++i) val[i] = t[cl * 8 + i][d];
        *(bf16x8*)&dst[(cl ^ sw) * 8] = val;
    }
}

// ---------- NT GEMM, m97 structure: BK=64, global_load_lds, swizzled ds_read ----------
// MODE 0: scatter epilogue with direct vT column write (fallback).
// MODE 2: scatter epilogue with row-major vrow (coalesced; vtrans_swz finishes).
// MODE 1: plain f32 out (GEMM2).
template<int MODE>
__launch_bounds__(256, 4)
__global__ void gemm_nt(const short* __restrict__ A, const short* __restrict__ Bt,
                        int M, int N, int K,
                        short* __restrict__ qrole, short* __restrict__ krole,
                        short* __restrict__ vT, float* __restrict__ out) {
    __shared__ __align__(16) short As[128][64];
    __shared__ __align__(16) short Bs[128][64];
    const int tid = threadIdx.x;
    const int lane = tid & 63;
    const int wid = tid >> 6;
    const int wm = wid >> 1, wn = wid & 1;
    const int m0 = blockIdx.y * 128, n0 = blockIdx.x * 128;
    const int r16 = lane & 15, g = lane >> 4;
    const int sw = r16 & 7;
    const char* Ab = (const char*)A;
    const char* Bb = (const char*)Bt;
    const long Kb = (long)K * 2;
    f32x4 acc[4][4] = {};
    for (int k0 = 0; k0 < K; k0 += 64) {
        #pragma unroll
        for (int it = 0; it < 4; ++it) {
            int id = it * 256 + tid;      // 0..1023 chunk ids
            int r = id >> 3, cch = id & 7;
            gload_lds16(Ab + (long)(m0 + r) * Kb + k0 * 2 + cch * 16, (char*)As + id * 16);
            gload_lds16(Bb + (long)(n0 + r) * Kb + k0 * 2 + cch * 16, (char*)Bs + id * 16);
        }
        __syncthreads();
        #pragma unroll
        for (int kk = 0; kk < 2; ++kk) {
            bf16x8 af[4], bfr[4];
            #pragma unroll
            for (int m = 0; m < 4; ++m)
                af[m] = *(const bf16x8*)&As[wm * 64 + m * 16 + r16][((kk * 4 + g) ^ sw) * 8];
            #pragma unroll
            for (int n = 0; n < 4; ++n)
                bfr[n] = *(const bf16x8*)&Bs[wn * 64 + n * 16 + r16][((kk * 4 + g) ^ sw) * 8];
            #pragma unroll
            for (int m = 0; m < 4; ++m)
                #pragma unroll
                for (int n = 0; n < 4; ++n)
                    acc[m][n] = __builtin_amdgcn_mfma_f32_16x16x32_bf16(af[m], bfr[n], acc[m][n], 0, 0, 0);
        }
        __syncthreads();
    }
    #pragma unroll
    for (int m = 0; m < 4; ++m) {
        #pragma unroll
        for (int n = 0; n < 4; ++n) {
            #pragma unroll
            for (int r = 0; r < 4; ++r) {
                int row = m0 + wm * 64 + m * 16 + g * 4 + r;
                int col = n0 + wn * 64 + n * 16 + r16;
                float v = acc[m][n][r];
                if (MODE != 1) {
                    int which = col >> 10, cc = col & 1023;
                    int h = cc >> 6, d = cc & 63;
                    int b = row >> 11, li = row & 2047;
                    int bh = b * 16 + h;
                    // q pre-scaled by (1/8)*log2(e) -> softmax runs in exp2 domain
                    if (which == 0)      qrole[((long)bh * 2048 + li) * 64 + d] = f2b(v * 0.18033688f);
                    else if (which == 1) krole[((long)bh * 2048 + li) * 64 + (d ^ ((li & 7) << 3))] = f2b(v);
                    else if (MODE == 2)  vT[((long)bh * 2048 + li) * 64 + d] = f2b(v);   // vrow, coalesced
                    else                 vT[((long)bh * 64 + d) * 2048 + ((li & ~63) | ((li & 63) ^ ((d & 7) << 3)))] = f2b(v);
                } else {
                    out[(long)row * N + col] = v;
                }
            }
        }
    }
}

// ---------- flash attention: 128 q-rows/block, 4 blocks/CU fully resident, hoisted K/V ----------
__launch_bounds__(256, 4)
__global__ void attn_kernel(const short* __restrict__ qrole, const short* __restrict__ krole,
                            const short* __restrict__ vT, short* __restrict__ y) {
    __shared__ __align__(16) short K_lds[2][64][64];
    __shared__ __align__(16) short V_lds[2][64][64];
    __shared__ __align__(16) short P_lds[4][16][64];
    const int tid = threadIdx.x, lane = tid & 63, w = tid >> 6;
    const int r16 = lane & 15, g = lane >> 4;
    const int idb = blockIdx.x;
    const int bh = idb & 63;           // id%8 == bh%8 -> one XCD per bh (KV L2-resident)
    const int c = 15 - ((idb >> 6) & 15);  // global LPT: descending T
    const int q0 = c << 7;
    const int T = 2 * c + 2;
    const short* qb = qrole + (long)bh * (2048 * 64);
    const char* kbyte = (const char*)(krole + (long)bh * (2048 * 64));
    const char* vbyte = (const char*)(vT + (long)bh * (64 * 2048));
    const int b = bh >> 4, h = bh & 15;

    bf16x8 qf[2][2];
    #pragma unroll
    for (int m = 0; m < 2; ++m)
        #pragma unroll
        for (int ks = 0; ks < 2; ++ks)
            qf[m][ks] = *(const bf16x8*)&qb[(long)(q0 + m * 64 + w * 16 + r16) * 64 + ks * 32 + g * 8];

    f32x4 o[2][4] = {};
    float mr[2], lr[2];                // lr = per-lane PARTIAL sum (reduced in epilogue)
    #pragma unroll
    for (int m = 0; m < 2; ++m) { mr[m] = -1e30f; lr[m] = 0.f; }

    // per-thread staging source pointers (advance by constants per tile)
    const int rr = tid >> 3, cch = tid & 7;
    const char* kg0 = kbyte + rr * 128 + cch * 16;            // rows 0..31
    const char* kg1 = kbyte + (32 + rr) * 128 + cch * 16;     // rows 32..63
    const char* vg0 = vbyte + rr * 4096 + cch * 16;
    const char* vg1 = vbyte + (32 + rr) * 4096 + cch * 16;
    char* Kb_ = (char*)&K_lds[0][0][0];
    char* Vb_ = (char*)&V_lds[0][0][0];
    const int ld0 = tid * 16, ld1 = (256 + tid) * 16;

    // stage tile 0 into buf 0
    gload_lds16(kg0, Kb_ + ld0);
    gload_lds16(kg1, Kb_ + ld1);
    gload_lds16(vg0, Vb_ + ld0);
    gload_lds16(vg1, Vb_ + ld1);

    const int psw = (r16 & 7) << 4;
    char* prow = (char*)&P_lds[w][r16][0];

    for (int t = 0; t < T; ++t) {
        __syncthreads();               // stage(t) landed (vmcnt drain) + all waves synced
        const int cur = t & 1;
        if (t + 1 < T) {               // issue stage(t+1): hidden under compute(t)
            long adv = (long)(t + 1) * 8192;
            long advv = (long)(t + 1) * 128;
            char* kdst = Kb_ + (cur ^ 1) * 8192;
            char* vdst = Vb_ + (cur ^ 1) * 8192;
            gload_lds16(kg0 + adv, kdst + ld0);
            gload_lds16(kg1 + adv, kdst + ld1);
            gload_lds16(vg0 + advv, vdst + ld0);
            gload_lds16(vg1 + advv, vdst + ld1);
        }
        const int jt = t << 6;
        const char* kbase = Kb_ + cur * 8192;
        const char* vbase = Vb_ + cur * 8192;

        // hoisted K/V fragment loads (no m-dependence): 16 ds_read_b128 once per tile
        bf16x8 kfr[2][4], vfr[2][4];
        #pragma unroll
        for (int ks = 0; ks < 2; ++ks)
            #pragma unroll
            for (int n = 0; n < 4; ++n) {
                const int off = ((ks * 64 + g * 16) ^ psw);
                kfr[ks][n] = *(const bf16x8*)(kbase + (n * 16 + r16) * 128 + off);
                vfr[ks][n] = *(const bf16x8*)(vbase + (n * 16 + r16) * 128 + off);
            }

        #pragma unroll
        for (int m = 0; m < 2; ++m) {
            const int qbase = q0 + m * 64 + w * 16;
            if (jt > qbase + 15) continue;   // frag fully masked (wave-uniform)

            // S^T = K * Q (exp2 domain)
            f32x4 s[4] = {};
            __builtin_amdgcn_s_setprio(1);
            #pragma unroll
            for (int ks = 0; ks < 2; ++ks)
                #pragma unroll
                for (int n = 0; n < 4; ++n)
                    s[n] = __builtin_amdgcn_mfma_f32_16x16x32_bf16(kfr[ks][n], qf[m][ks], s[n], 0, 0, 0);
            __builtin_amdgcn_s_setprio(0);
            if (jt + 63 > qbase) {           // diagonal: mask j > i
                const int i = qbase + r16;
                #pragma unroll
                for (int n = 0; n < 4; ++n)
                    #pragma unroll
                    for (int r = 0; r < 4; ++r)
                        if (jt + n * 16 + g * 4 + r > i) s[n][r] = -1e30f;
            }
            // row max: max3-shaped tree
            float a0 = fmaxf(fmaxf(s[0][0], s[0][1]), s[0][2]);
            float a1 = fmaxf(fmaxf(s[0][3], s[1][0]), s[1][1]);
            float a2 = fmaxf(fmaxf(s[1][2], s[1][3]), s[2][0]);
            float a3 = fmaxf(fmaxf(s[2][1], s[2][2]), s[2][3]);
            float a4 = fmaxf(fmaxf(s[3][0], s[3][1]), s[3][2]);
            float b0 = fmaxf(fmaxf(a0, a1), a2);
            float b1 = fmaxf(fmaxf(a3, a4), s[3][3]);
            float tm = fmaxf(b0, b1);
            tm = fmaxf(tm, __shfl_xor(tm, 16));
            tm = fmaxf(tm, __shfl_xor(tm, 32));
            // defer-max (T13), log2 units (11.5 ~= 8 nats)
            if (__any(tm > mr[m] + 11.5f)) {
                float mn = fmaxf(mr[m], tm);
                float sc = fexp2(mr[m] - mn);   // uniform across g-group -> scales partials exactly
                mr[m] = mn;
                lr[m] *= sc;
                float scr[4];
                #pragma unroll
                for (int r = 0; r < 4; ++r) scr[r] = __shfl(sc, (g << 2) + r);
                #pragma unroll
                for (int nd = 0; nd < 4; ++nd)
                    #pragma unroll
                    for (int r = 0; r < 4; ++r)
                        o[m][nd][r] *= scr[r];
            }
            // p = exp2(s - m) via packed subtract, cvt_pk pack -> swizzled P_lds
            const float nm = -mr[m];
            f32x2 nm2; nm2.x = nm; nm2.y = nm;
            float p[4][4];
            #pragma unroll
            for (int n = 0; n < 4; ++n) {
                f32x2 lo; lo.x = s[n][0]; lo.y = s[n][1];
                f32x2 hi; hi.x = s[n][2]; hi.y = s[n][3];
                f32x2 e01 = pk_add(lo, nm2);
                f32x2 e23 = pk_add(hi, nm2);
                p[n][0] = fexp2(e01.x);
                p[n][1] = fexp2(e01.y);
                p[n][2] = fexp2(e23.x);
                p[n][3] = fexp2(e23.y);
                unsigned w0 = cvt_pk_bf16(p[n][0], p[n][1]);
                unsigned w1 = cvt_pk_bf16(p[n][2], p[n][3]);
                unsigned long long dw = ((unsigned long long)w1 << 32) | w0;
                *(unsigned long long*)(prow + ((n * 32 + g * 8) ^ psw)) = dw;
            }
            // per-lane partial sum only (cross-lane reduce deferred to epilogue)
            float l0 = (p[0][0] + p[0][1]) + (p[0][2] + p[0][3]);
            float l1 = (p[1][0] + p[1][1]) + (p[1][2] + p[1][3]);
            float l2 = (p[2][0] + p[2][1]) + (p[2][2] + p[2][3]);
            float l3 = (p[3][0] + p[3][1]) + (p[3][2] + p[3][3]);
            lr[m] += (l0 + l1) + (l2 + l3);
            // PV (V already in registers)
            __builtin_amdgcn_s_setprio(1);
            #pragma unroll
            for (int ks = 0; ks < 2; ++ks) {
                bf16x8 pf = *(const bf16x8*)(prow + ((ks * 64 + g * 16) ^ psw));
                #pragma unroll
                for (int nd = 0; nd < 4; ++nd)
                    o[m][nd] = __builtin_amdgcn_mfma_f32_16x16x32_bf16(pf, vfr[ks][nd], o[m][nd], 0, 0, 0);
            }
            __builtin_amdgcn_s_setprio(0);
        }
    }
    // epilogue: reduce partial lr across g-group, then write y with GEMM2's k-chunk pre-swizzle
    #pragma unroll
    for (int m = 0; m < 2; ++m) {
        lr[m] += __shfl_xor(lr[m], 16);
        lr[m] += __shfl_xor(lr[m], 32);
        float inv[4];
        #pragma unroll
        for (int r = 0; r < 4; ++r) inv[r] = 1.0f / __shfl(lr[m], (g << 2) + r);
        const int li0 = q0 + m * 64 + w * 16 + (g << 2);
        #pragma unroll
        for (int nd = 0; nd < 4; ++nd)
            #pragma unroll
            for (int r = 0; r < 4; ++r) {
                int li = li0 + r;
                int sub = ((nd * 2 + (r16 >> 3)) ^ li) & 7;
                int kp = h * 64 + sub * 8 + (r16 & 7);
                y[(long)(b * 2048 + li) * 1024 + kp] = f2b(o[m][nd][r] * inv[r]);
            }
    }
}

extern "C" void kernel_launch(void* const* d_in, const int* in_sizes, int n_in,
                              void* d_out, int out_size, void* d_ws, size_t ws_size,
                              hipStream_t stream) {
    const float* x  = (const float*)d_in[0];
    const float* Wa = (const float*)d_in[1];
    const float* Wf = (const float*)d_in[2];
    float* out = (float*)d_out;
    char* ws = (char*)d_ws;
    short* xb  = (short*)(ws);                   // 16 MB (8192x1024 bf16, pre-swz); reused as y
    short* wab = (short*)(ws + (16l << 20));     // 6 MB  (3072x1024 bf16, T + pre-swz)
    short* wfb = (short*)(ws + (22l << 20));     // 2 MB  (1024x1024 bf16, T + pre-swz)
    short* qr  = (short*)(ws + (24l << 20));     // 16 MB [B,H,L,64] (pre-scaled by log2e/8)
    short* kr  = (short*)(ws + (40l << 20));     // 16 MB [B,H,L,64] (d-swizzled)
    short* vt  = (short*)(ws + (56l << 20));     // 16 MB [B,H,64,L] (j-swizzled per 64-tile)
    short* vrow = (short*)(ws + (72l << 20));    // 16 MB [B,H,L,64] row-major V staging

    conv_swz<<<2048, 256, 0, stream>>>(x, xb, (long)8192 * 128);
    transpose_swz<<<dim3(96, 32), dim3(32, 8), 0, stream>>>(Wa, wab, 1024, 3072);
    transpose_swz<<<dim3(32, 32), dim3(32, 8), 0, stream>>>(Wf, wfb, 1024, 1024);
    if (ws_size >= (89ull << 20)) {
        gemm_nt<2><<<dim3(24, 64), 256, 0, stream>>>(xb, wab, 8192, 3072, 1024, qr, kr, vrow, nullptr);
        vtrans_swz<<<2048, 256, 0, stream>>>(vrow, vt);
    } else {
        gemm_nt<0><<<dim3(24, 64), 256, 0, stream>>>(xb, wab, 8192, 3072, 1024, qr, kr, vt, nullptr);
    }
    attn_kernel<<<1024, 256, 0, stream>>>(qr, kr, vt, xb);
    gemm_nt<1><<<dim3(8, 64), 256, 0, stream>>>(xb, wfb, 8192, 1024, 1024, nullptr, nullptr, nullptr, out);
}

// Round 15
// 171.662 us; speedup vs baseline: 2.0176x; 2.0176x over previous
//
#include <hip/hip_runtime.h>
#include <hip/hip_bf16.h>

typedef __attribute__((ext_vector_type(8))) short bf16x8;
typedef __attribute__((ext_vector_type(4))) float f32x4;
typedef __attribute__((ext_vector_type(2))) float f32x2;

__device__ __forceinline__ short f2b(float f) {
    unsigned u = __builtin_bit_cast(unsigned, f);
    unsigned r = (u + 0x7FFFu + ((u >> 16) & 1u)) >> 16;
    return (short)r;
}

__device__ __forceinline__ unsigned cvt_pk_bf16(float lo, float hi) {
    unsigned r;
    asm("v_cvt_pk_bf16_f32 %0, %1, %2" : "=v"(r) : "v"(lo), "v"(hi));
    return r;
}

__device__ __forceinline__ float fexp2(float x) {
    float r;
    asm("v_exp_f32 %0, %1" : "=v"(r) : "v"(x));
    return r;
}

__device__ __forceinline__ f32x2 pk_add(f32x2 a, f32x2 b) {
    f32x2 d;
    asm("v_pk_add_f32 %0, %1, %2" : "=v"(d) : "v"(a), "v"(b));
    return d;
}

__device__ __forceinline__ void gload_lds16(const void* g, void* l) {
    __builtin_amdgcn_global_load_lds((const __attribute__((address_space(1))) unsigned*)g,
                                     (__attribute__((address_space(3))) unsigned*)l, 16, 0, 0);
}

// ---------- convert x f32->bf16, k-chunk pre-swizzled (chunk^row&7 within 64-group) ----------
__global__ void conv_swz(const float* __restrict__ in, short* __restrict__ out, long nch) {
    long i = (long)blockIdx.x * blockDim.x + threadIdx.x;
    long stride = (long)gridDim.x * blockDim.x;
    for (; i < nch; i += stride) {
        long m = i >> 7;            // row (K=1024 -> 128 chunks of 8)
        int ch = (int)(i & 127);
        int p = (ch & ~7) | ((ch ^ (int)m) & 7);
        const float4* s = (const float4*)(in + i * 8);
        float4 a = s[0], b = s[1];
        bf16x8 ov;
        ov[0] = f2b(a.x); ov[1] = f2b(a.y); ov[2] = f2b(a.z); ov[3] = f2b(a.w);
        ov[4] = f2b(b.x); ov[5] = f2b(b.y); ov[6] = f2b(b.z); ov[7] = f2b(b.w);
        *(bf16x8*)(out + (m << 10) + p * 8) = ov;
    }
}

// ---------- transpose + convert + k-chunk pre-swizzle: in [R=K][C] f32 -> outT [C][K] bf16 ----------
__global__ void transpose_swz(const float* __restrict__ in, short* __restrict__ outT, int R, int C) {
    __shared__ float t[32][33];
    int c0 = blockIdx.x * 32, r0 = blockIdx.y * 32;
    int tx = threadIdx.x, ty = threadIdx.y; // 32 x 8
    #pragma unroll
    for (int j = 0; j < 4; ++j)
        t[ty + j * 8][tx] = in[(long)(r0 + ty + j * 8) * C + c0 + tx];
    __syncthreads();
    #pragma unroll
    for (int j = 0; j < 4; ++j) {
        int n = c0 + ty + j * 8;    // output row
        int k = r0 + tx;            // k index
        int kp = (k & ~63) | ((((k >> 3) ^ n) & 7) << 3) | (k & 7);
        outT[(long)n * R + kp] = f2b(t[tx][ty + j * 8]);
    }
}

// ---------- v transpose: vrow [bh][li][64] -> vT [bh][64][2048] with j-swizzle ----------
__global__ void vtrans_swz(const short* __restrict__ vrow, short* __restrict__ vT) {
    __shared__ short t[64][66];
    const int bh = blockIdx.x & 63;
    const int li0 = ((blockIdx.x >> 6) & 31) << 6;
    const int tid = threadIdx.x;
    const short* src = vrow + ((long)bh * 2048 + li0) * 64;
    {
        int id0 = tid, id1 = tid + 256;      // 512 16B-chunks: 64 rows x 8 chunks
        int r0 = id0 >> 3, c0 = id0 & 7;
        int r1 = id1 >> 3, c1 = id1 & 7;
        *(bf16x8*)&t[r0][c0 * 8] = *(const bf16x8*)&src[r0 * 64 + c0 * 8];
        *(bf16x8*)&t[r1][c1 * 8] = *(const bf16x8*)&src[r1 * 64 + c1 * 8];
    }
    __syncthreads();
    const int d = tid >> 2, part = tid & 3;  // each thread: row d, li-chunks 2*part, 2*part+1
    short* dst = vT + ((long)bh * 64 + d) * 2048 + li0;
    const int sw = d & 7;
    #pragma unroll
    for (int cc = 0; cc < 2; ++cc) {
        int cl = part * 2 + cc;              // source li-chunk (8 elems)
        bf16x8 val;
        #pragma unroll
        for (int i = 0; i < 8; ++i) val[i] = t[cl * 8 + i][d];
        *(bf16x8*)&dst[(cl ^ sw) * 8] = val;
    }
}

// ---------- NT GEMM, m97 structure: BK=64, global_load_lds, swizzled ds_read ----------
// MODE 0: scatter epilogue with direct vT column write (fallback).
// MODE 2: scatter epilogue with row-major vrow (coalesced; vtrans_swz finishes).
// MODE 1: plain f32 out (GEMM2).
template<int MODE>
__launch_bounds__(256, 4)
__global__ void gemm_nt(const short* __restrict__ A, const short* __restrict__ Bt,
                        int M, int N, int K,
                        short* __restrict__ qrole, short* __restrict__ krole,
                        short* __restrict__ vT, float* __restrict__ out) {
    __shared__ __align__(16) short As[128][64];
    __shared__ __align__(16) short Bs[128][64];
    const int tid = threadIdx.x;
    const int lane = tid & 63;
    const int wid = tid >> 6;
    const int wm = wid >> 1, wn = wid & 1;
    const int m0 = blockIdx.y * 128, n0 = blockIdx.x * 128;
    const int r16 = lane & 15, g = lane >> 4;
    const int sw = r16 & 7;
    const char* Ab = (const char*)A;
    const char* Bb = (const char*)Bt;
    const long Kb = (long)K * 2;
    f32x4 acc[4][4] = {};
    for (int k0 = 0; k0 < K; k0 += 64) {
        #pragma unroll
        for (int it = 0; it < 4; ++it) {
            int id = it * 256 + tid;      // 0..1023 chunk ids
            int r = id >> 3, cch = id & 7;
            gload_lds16(Ab + (long)(m0 + r) * Kb + k0 * 2 + cch * 16, (char*)As + id * 16);
            gload_lds16(Bb + (long)(n0 + r) * Kb + k0 * 2 + cch * 16, (char*)Bs + id * 16);
        }
        __syncthreads();
        #pragma unroll
        for (int kk = 0; kk < 2; ++kk) {
            bf16x8 af[4], bfr[4];
            #pragma unroll
            for (int m = 0; m < 4; ++m)
                af[m] = *(const bf16x8*)&As[wm * 64 + m * 16 + r16][((kk * 4 + g) ^ sw) * 8];
            #pragma unroll
            for (int n = 0; n < 4; ++n)
                bfr[n] = *(const bf16x8*)&Bs[wn * 64 + n * 16 + r16][((kk * 4 + g) ^ sw) * 8];
            #pragma unroll
            for (int m = 0; m < 4; ++m)
                #pragma unroll
                for (int n = 0; n < 4; ++n)
                    acc[m][n] = __builtin_amdgcn_mfma_f32_16x16x32_bf16(af[m], bfr[n], acc[m][n], 0, 0, 0);
        }
        __syncthreads();
    }
    #pragma unroll
    for (int m = 0; m < 4; ++m) {
        #pragma unroll
        for (int n = 0; n < 4; ++n) {
            #pragma unroll
            for (int r = 0; r < 4; ++r) {
                int row = m0 + wm * 64 + m * 16 + g * 4 + r;
                int col = n0 + wn * 64 + n * 16 + r16;
                float v = acc[m][n][r];
                if (MODE != 1) {
                    int which = col >> 10, cc = col & 1023;
                    int h = cc >> 6, d = cc & 63;
                    int b = row >> 11, li = row & 2047;
                    int bh = b * 16 + h;
                    // q pre-scaled by (1/8)*log2(e) -> softmax runs in exp2 domain
                    if (which == 0)      qrole[((long)bh * 2048 + li) * 64 + d] = f2b(v * 0.18033688f);
                    else if (which == 1) krole[((long)bh * 2048 + li) * 64 + (d ^ ((li & 7) << 3))] = f2b(v);
                    else if (MODE == 2)  vT[((long)bh * 2048 + li) * 64 + d] = f2b(v);   // vrow, coalesced
                    else                 vT[((long)bh * 64 + d) * 2048 + ((li & ~63) | ((li & 63) ^ ((d & 7) << 3)))] = f2b(v);
                } else {
                    out[(long)row * N + col] = v;
                }
            }
        }
    }
}

// ---------- flash attention: 128 q-rows/block, global LPT, 3 blocks/CU, hoisted K/V ----------
__launch_bounds__(256, 3)
__global__ void attn_kernel(const short* __restrict__ qrole, const short* __restrict__ krole,
                            const short* __restrict__ vT, short* __restrict__ y) {
    __shared__ __align__(16) short K_lds[2][64][64];
    __shared__ __align__(16) short V_lds[2][64][64];
    __shared__ __align__(16) short P_lds[4][16][64];
    const int tid = threadIdx.x, lane = tid & 63, w = tid >> 6;
    const int r16 = lane & 15, g = lane >> 4;
    const int idb = blockIdx.x;
    const int bh = idb & 63;           // id%8 == bh%8 -> one XCD per bh (KV L2-resident)
    const int c = 15 - ((idb >> 6) & 15);  // global LPT: descending T
    const int q0 = c << 7;
    const int T = 2 * c + 2;
    const short* qb = qrole + (long)bh * (2048 * 64);
    const char* kbyte = (const char*)(krole + (long)bh * (2048 * 64));
    const char* vbyte = (const char*)(vT + (long)bh * (64 * 2048));
    const int b = bh >> 4, h = bh & 15;

    bf16x8 qf[2][2];
    #pragma unroll
    for (int m = 0; m < 2; ++m)
        #pragma unroll
        for (int ks = 0; ks < 2; ++ks)
            qf[m][ks] = *(const bf16x8*)&qb[(long)(q0 + m * 64 + w * 16 + r16) * 64 + ks * 32 + g * 8];

    f32x4 o[2][4] = {};
    float mr[2], lr[2];
    #pragma unroll
    for (int m = 0; m < 2; ++m) { mr[m] = -1e30f; lr[m] = 0.f; }

    // per-thread staging source pointers (advance by constants per tile)
    const int rr = tid >> 3, cch = tid & 7;
    const char* kg0 = kbyte + rr * 128 + cch * 16;            // rows 0..31
    const char* kg1 = kbyte + (32 + rr) * 128 + cch * 16;     // rows 32..63
    const char* vg0 = vbyte + rr * 4096 + cch * 16;
    const char* vg1 = vbyte + (32 + rr) * 4096 + cch * 16;
    char* Kb_ = (char*)&K_lds[0][0][0];
    char* Vb_ = (char*)&V_lds[0][0][0];
    const int ld0 = tid * 16, ld1 = (256 + tid) * 16;

    // stage tile 0 into buf 0
    gload_lds16(kg0, Kb_ + ld0);
    gload_lds16(kg1, Kb_ + ld1);
    gload_lds16(vg0, Vb_ + ld0);
    gload_lds16(vg1, Vb_ + ld1);

    const int psw = (r16 & 7) << 4;
    char* prow = (char*)&P_lds[w][r16][0];

    for (int t = 0; t < T; ++t) {
        __syncthreads();               // stage(t) landed (vmcnt drain) + all waves synced
        const int cur = t & 1;
        if (t + 1 < T) {               // issue stage(t+1): hidden under compute(t)
            long adv = (long)(t + 1) * 8192;
            long advv = (long)(t + 1) * 128;
            char* kdst = Kb_ + (cur ^ 1) * 8192;
            char* vdst = Vb_ + (cur ^ 1) * 8192;
            gload_lds16(kg0 + adv, kdst + ld0);
            gload_lds16(kg1 + adv, kdst + ld1);
            gload_lds16(vg0 + advv, vdst + ld0);
            gload_lds16(vg1 + advv, vdst + ld1);
        }
        const int jt = t << 6;
        const char* kbase = Kb_ + cur * 8192;
        const char* vbase = Vb_ + cur * 8192;

        // hoisted K/V fragment loads (no m-dependence): 16 ds_read_b128 once per tile
        bf16x8 kfr[2][4], vfr[2][4];
        #pragma unroll
        for (int ks = 0; ks < 2; ++ks)
            #pragma unroll
            for (int n = 0; n < 4; ++n) {
                const int off = ((ks * 64 + g * 16) ^ psw);
                kfr[ks][n] = *(const bf16x8*)(kbase + (n * 16 + r16) * 128 + off);
                vfr[ks][n] = *(const bf16x8*)(vbase + (n * 16 + r16) * 128 + off);
            }

        #pragma unroll
        for (int m = 0; m < 2; ++m) {
            const int qbase = q0 + m * 64 + w * 16;
            if (jt > qbase + 15) continue;   // frag fully masked (wave-uniform)

            // S^T = K * Q (exp2 domain)
            f32x4 s[4] = {};
            __builtin_amdgcn_s_setprio(1);
            #pragma unroll
            for (int ks = 0; ks < 2; ++ks)
                #pragma unroll
                for (int n = 0; n < 4; ++n)
                    s[n] = __builtin_amdgcn_mfma_f32_16x16x32_bf16(kfr[ks][n], qf[m][ks], s[n], 0, 0, 0);
            __builtin_amdgcn_s_setprio(0);
            if (jt + 63 > qbase) {           // diagonal: mask j > i
                const int i = qbase + r16;
                #pragma unroll
                for (int n = 0; n < 4; ++n)
                    #pragma unroll
                    for (int r = 0; r < 4; ++r)
                        if (jt + n * 16 + g * 4 + r > i) s[n][r] = -1e30f;
            }
            // row max: max3-shaped tree
            float a0 = fmaxf(fmaxf(s[0][0], s[0][1]), s[0][2]);
            float a1 = fmaxf(fmaxf(s[0][3], s[1][0]), s[1][1]);
            float a2 = fmaxf(fmaxf(s[1][2], s[1][3]), s[2][0]);
            float a3 = fmaxf(fmaxf(s[2][1], s[2][2]), s[2][3]);
            float a4 = fmaxf(fmaxf(s[3][0], s[3][1]), s[3][2]);
            float b0 = fmaxf(fmaxf(a0, a1), a2);
            float b1 = fmaxf(fmaxf(a3, a4), s[3][3]);
            float tm = fmaxf(b0, b1);
            tm = fmaxf(tm, __shfl_xor(tm, 16));
            tm = fmaxf(tm, __shfl_xor(tm, 32));
            // defer-max (T13), log2 units (11.5 ~= 8 nats)
            if (__any(tm > mr[m] + 11.5f)) {
                float mn = fmaxf(mr[m], tm);
                float sc = fexp2(mr[m] - mn);
                mr[m] = mn;
                lr[m] *= sc;
                float scr[4];
                #pragma unroll
                for (int r = 0; r < 4; ++r) scr[r] = __shfl(sc, (g << 2) + r);
                #pragma unroll
                for (int nd = 0; nd < 4; ++nd)
                    #pragma unroll
                    for (int r = 0; r < 4; ++r)
                        o[m][nd][r] *= scr[r];
            }
            // p = exp2(s - m) via packed subtract, tree sum, cvt_pk pack -> swizzled P_lds
            const float nm = -mr[m];
            f32x2 nm2; nm2.x = nm; nm2.y = nm;
            float p[4][4];
            #pragma unroll
            for (int n = 0; n < 4; ++n) {
                f32x2 lo; lo.x = s[n][0]; lo.y = s[n][1];
                f32x2 hi; hi.x = s[n][2]; hi.y = s[n][3];
                f32x2 e01 = pk_add(lo, nm2);
                f32x2 e23 = pk_add(hi, nm2);
                p[n][0] = fexp2(e01.x);
                p[n][1] = fexp2(e01.y);
                p[n][2] = fexp2(e23.x);
                p[n][3] = fexp2(e23.y);
                unsigned w0 = cvt_pk_bf16(p[n][0], p[n][1]);
                unsigned w1 = cvt_pk_bf16(p[n][2], p[n][3]);
                unsigned long long dw = ((unsigned long long)w1 << 32) | w0;
                *(unsigned long long*)(prow + ((n * 32 + g * 8) ^ psw)) = dw;
            }
            float l0 = (p[0][0] + p[0][1]) + (p[0][2] + p[0][3]);
            float l1 = (p[1][0] + p[1][1]) + (p[1][2] + p[1][3]);
            float l2 = (p[2][0] + p[2][1]) + (p[2][2] + p[2][3]);
            float l3 = (p[3][0] + p[3][1]) + (p[3][2] + p[3][3]);
            float lsum = (l0 + l1) + (l2 + l3);
            lsum += __shfl_xor(lsum, 16);
            lsum += __shfl_xor(lsum, 32);
            lr[m] += lsum;
            // PV (V already in registers)
            __builtin_amdgcn_s_setprio(1);
            #pragma unroll
            for (int ks = 0; ks < 2; ++ks) {
                bf16x8 pf = *(const bf16x8*)(prow + ((ks * 64 + g * 16) ^ psw));
                #pragma unroll
                for (int nd = 0; nd < 4; ++nd)
                    o[m][nd] = __builtin_amdgcn_mfma_f32_16x16x32_bf16(pf, vfr[ks][nd], o[m][nd], 0, 0, 0);
            }
            __builtin_amdgcn_s_setprio(0);
        }
    }
    // epilogue: write y with GEMM2's k-chunk pre-swizzle
    #pragma unroll
    for (int m = 0; m < 2; ++m) {
        float inv[4];
        #pragma unroll
        for (int r = 0; r < 4; ++r) inv[r] = 1.0f / __shfl(lr[m], (g << 2) + r);
        const int li0 = q0 + m * 64 + w * 16 + (g << 2);
        #pragma unroll
        for (int nd = 0; nd < 4; ++nd)
            #pragma unroll
            for (int r = 0; r < 4; ++r) {
                int li = li0 + r;
                int sub = ((nd * 2 + (r16 >> 3)) ^ li) & 7;
                int kp = h * 64 + sub * 8 + (r16 & 7);
                y[(long)(b * 2048 + li) * 1024 + kp] = f2b(o[m][nd][r] * inv[r]);
            }
    }
}

extern "C" void kernel_launch(void* const* d_in, const int* in_sizes, int n_in,
                              void* d_out, int out_size, void* d_ws, size_t ws_size,
                              hipStream_t stream) {
    const float* x  = (const float*)d_in[0];
    const float* Wa = (const float*)d_in[1];
    const float* Wf = (const float*)d_in[2];
    float* out = (float*)d_out;
    char* ws = (char*)d_ws;
    short* xb  = (short*)(ws);                   // 16 MB (8192x1024 bf16, pre-swz); reused as y
    short* wab = (short*)(ws + (16l << 20));     // 6 MB  (3072x1024 bf16, T + pre-swz)
    short* wfb = (short*)(ws + (22l << 20));     // 2 MB  (1024x1024 bf16, T + pre-swz)
    short* qr  = (short*)(ws + (24l << 20));     // 16 MB [B,H,L,64] (pre-scaled by log2e/8)
    short* kr  = (short*)(ws + (40l << 20));     // 16 MB [B,H,L,64] (d-swizzled)
    short* vt  = (short*)(ws + (56l << 20));     // 16 MB [B,H,64,L] (j-swizzled per 64-tile)
    short* vrow = (short*)(ws + (72l << 20));    // 16 MB [B,H,L,64] row-major V staging

    conv_swz<<<2048, 256, 0, stream>>>(x, xb, (long)8192 * 128);
    transpose_swz<<<dim3(96, 32), dim3(32, 8), 0, stream>>>(Wa, wab, 1024, 3072);
    transpose_swz<<<dim3(32, 32), dim3(32, 8), 0, stream>>>(Wf, wfb, 1024, 1024);
    if (ws_size >= (89ull << 20)) {
        gemm_nt<2><<<dim3(24, 64), 256, 0, stream>>>(xb, wab, 8192, 3072, 1024, qr, kr, vrow, nullptr);
        vtrans_swz<<<2048, 256, 0, stream>>>(vrow, vt);
    } else {
        gemm_nt<0><<<dim3(24, 64), 256, 0, stream>>>(xb, wab, 8192, 3072, 1024, qr, kr, vt, nullptr);
    }
    attn_kernel<<<1024, 256, 0, stream>>>(qr, kr, vt, xb);
    gemm_nt<1><<<dim3(8, 64), 256, 0, stream>>>(xb, wfb, 8192, 1024, 1024, nullptr, nullptr, nullptr, out);
}

// Round 16
// 168.721 us; speedup vs baseline: 2.0528x; 1.0174x over previous
//
#include <hip/hip_runtime.h>
#include <hip/hip_bf16.h>

typedef __attribute__((ext_vector_type(8))) short bf16x8;
typedef __attribute__((ext_vector_type(4))) float f32x4;
typedef __attribute__((ext_vector_type(2))) float f32x2;

__device__ __forceinline__ short f2b(float f) {
    unsigned u = __builtin_bit_cast(unsigned, f);
    unsigned r = (u + 0x7FFFu + ((u >> 16) & 1u)) >> 16;
    return (short)r;
}

__device__ __forceinline__ unsigned cvt_pk_bf16(float lo, float hi) {
    unsigned r;
    asm("v_cvt_pk_bf16_f32 %0, %1, %2" : "=v"(r) : "v"(lo), "v"(hi));
    return r;
}

__device__ __forceinline__ float fexp2(float x) {
    float r;
    asm("v_exp_f32 %0, %1" : "=v"(r) : "v"(x));
    return r;
}

__device__ __forceinline__ f32x2 pk_add(f32x2 a, f32x2 b) {
    f32x2 d;
    asm("v_pk_add_f32 %0, %1, %2" : "=v"(d) : "v"(a), "v"(b));
    return d;
}

__device__ __forceinline__ void gload_lds16(const void* g, void* l) {
    __builtin_amdgcn_global_load_lds((const __attribute__((address_space(1))) unsigned*)g,
                                     (__attribute__((address_space(3))) unsigned*)l, 16, 0, 0);
}

// ---------- convert x f32->bf16, k-chunk pre-swizzled (chunk^row&7 within 64-group) ----------
__global__ void conv_swz(const float* __restrict__ in, short* __restrict__ out, long nch) {
    long i = (long)blockIdx.x * blockDim.x + threadIdx.x;
    long stride = (long)gridDim.x * blockDim.x;
    for (; i < nch; i += stride) {
        long m = i >> 7;            // row (K=1024 -> 128 chunks of 8)
        int ch = (int)(i & 127);
        int p = (ch & ~7) | ((ch ^ (int)m) & 7);
        const float4* s = (const float4*)(in + i * 8);
        float4 a = s[0], b = s[1];
        bf16x8 ov;
        ov[0] = f2b(a.x); ov[1] = f2b(a.y); ov[2] = f2b(a.z); ov[3] = f2b(a.w);
        ov[4] = f2b(b.x); ov[5] = f2b(b.y); ov[6] = f2b(b.z); ov[7] = f2b(b.w);
        *(bf16x8*)(out + (m << 10) + p * 8) = ov;
    }
}

// ---------- transpose + convert + k-chunk pre-swizzle: in [R=K][C] f32 -> outT [C][K] bf16 ----------
__global__ void transpose_swz(const float* __restrict__ in, short* __restrict__ outT, int R, int C) {
    __shared__ float t[32][33];
    int c0 = blockIdx.x * 32, r0 = blockIdx.y * 32;
    int tx = threadIdx.x, ty = threadIdx.y; // 32 x 8
    #pragma unroll
    for (int j = 0; j < 4; ++j)
        t[ty + j * 8][tx] = in[(long)(r0 + ty + j * 8) * C + c0 + tx];
    __syncthreads();
    #pragma unroll
    for (int j = 0; j < 4; ++j) {
        int n = c0 + ty + j * 8;    // output row
        int k = r0 + tx;            // k index
        int kp = (k & ~63) | ((((k >> 3) ^ n) & 7) << 3) | (k & 7);
        outT[(long)n * R + kp] = f2b(t[tx][ty + j * 8]);
    }
}

// ---------- v transpose: vrow [bh][li][64] -> vT [bh][64][2048] with j-swizzle ----------
__global__ void vtrans_swz(const short* __restrict__ vrow, short* __restrict__ vT) {
    __shared__ short t[64][66];
    const int bh = blockIdx.x & 63;
    const int li0 = ((blockIdx.x >> 6) & 31) << 6;
    const int tid = threadIdx.x;
    const short* src = vrow + ((long)bh * 2048 + li0) * 64;
    {
        int id0 = tid, id1 = tid + 256;      // 512 16B-chunks: 64 rows x 8 chunks
        int r0 = id0 >> 3, c0 = id0 & 7;
        int r1 = id1 >> 3, c1 = id1 & 7;
        *(bf16x8*)&t[r0][c0 * 8] = *(const bf16x8*)&src[r0 * 64 + c0 * 8];
        *(bf16x8*)&t[r1][c1 * 8] = *(const bf16x8*)&src[r1 * 64 + c1 * 8];
    }
    __syncthreads();
    const int d = tid >> 2, part = tid & 3;  // each thread: row d, li-chunks 2*part, 2*part+1
    short* dst = vT + ((long)bh * 64 + d) * 2048 + li0;
    const int sw = d & 7;
    #pragma unroll
    for (int cc = 0; cc < 2; ++cc) {
        int cl = part * 2 + cc;              // source li-chunk (8 elems)
        bf16x8 val;
        #pragma unroll
        for (int i = 0; i < 8; ++i) val[i] = t[cl * 8 + i][d];
        *(bf16x8*)&dst[(cl ^ sw) * 8] = val;
    }
}

// ---------- NT GEMM, m97 structure: BK=64, global_load_lds, swizzled ds_read ----------
// MODE 0: scatter epilogue with direct vT column write (fallback).
// MODE 2: scatter epilogue with row-major vrow (coalesced; vtrans_swz finishes).
// MODE 1: plain f32 out (GEMM2).
template<int MODE>
__launch_bounds__(256, 4)
__global__ void gemm_nt(const short* __restrict__ A, const short* __restrict__ Bt,
                        int M, int N, int K,
                        short* __restrict__ qrole, short* __restrict__ krole,
                        short* __restrict__ vT, float* __restrict__ out) {
    __shared__ __align__(16) short As[128][64];
    __shared__ __align__(16) short Bs[128][64];
    const int tid = threadIdx.x;
    const int lane = tid & 63;
    const int wid = tid >> 6;
    const int wm = wid >> 1, wn = wid & 1;
    const int m0 = blockIdx.y * 128, n0 = blockIdx.x * 128;
    const int r16 = lane & 15, g = lane >> 4;
    const int sw = r16 & 7;
    const char* Ab = (const char*)A;
    const char* Bb = (const char*)Bt;
    const long Kb = (long)K * 2;
    f32x4 acc[4][4] = {};
    for (int k0 = 0; k0 < K; k0 += 64) {
        #pragma unroll
        for (int it = 0; it < 4; ++it) {
            int id = it * 256 + tid;      // 0..1023 chunk ids
            int r = id >> 3, cch = id & 7;
            gload_lds16(Ab + (long)(m0 + r) * Kb + k0 * 2 + cch * 16, (char*)As + id * 16);
            gload_lds16(Bb + (long)(n0 + r) * Kb + k0 * 2 + cch * 16, (char*)Bs + id * 16);
        }
        __syncthreads();
        #pragma unroll
        for (int kk = 0; kk < 2; ++kk) {
            bf16x8 af[4], bfr[4];
            #pragma unroll
            for (int m = 0; m < 4; ++m)
                af[m] = *(const bf16x8*)&As[wm * 64 + m * 16 + r16][((kk * 4 + g) ^ sw) * 8];
            #pragma unroll
            for (int n = 0; n < 4; ++n)
                bfr[n] = *(const bf16x8*)&Bs[wn * 64 + n * 16 + r16][((kk * 4 + g) ^ sw) * 8];
            #pragma unroll
            for (int m = 0; m < 4; ++m)
                #pragma unroll
                for (int n = 0; n < 4; ++n)
                    acc[m][n] = __builtin_amdgcn_mfma_f32_16x16x32_bf16(af[m], bfr[n], acc[m][n], 0, 0, 0);
        }
        __syncthreads();
    }
    #pragma unroll
    for (int m = 0; m < 4; ++m) {
        #pragma unroll
        for (int n = 0; n < 4; ++n) {
            #pragma unroll
            for (int r = 0; r < 4; ++r) {
                int row = m0 + wm * 64 + m * 16 + g * 4 + r;
                int col = n0 + wn * 64 + n * 16 + r16;
                float v = acc[m][n][r];
                if (MODE != 1) {
                    int which = col >> 10, cc = col & 1023;
                    int h = cc >> 6, d = cc & 63;
                    int b = row >> 11, li = row & 2047;
                    int bh = b * 16 + h;
                    // q pre-scaled by (1/8)*log2(e) -> softmax runs in exp2 domain
                    if (which == 0)      qrole[((long)bh * 2048 + li) * 64 + d] = f2b(v * 0.18033688f);
                    else if (which == 1) krole[((long)bh * 2048 + li) * 64 + (d ^ ((li & 7) << 3))] = f2b(v);
                    else if (MODE == 2)  vT[((long)bh * 2048 + li) * 64 + d] = f2b(v);   // vrow, coalesced
                    else                 vT[((long)bh * 64 + d) * 2048 + ((li & ~63) | ((li & 63) ^ ((d & 7) << 3)))] = f2b(v);
                } else {
                    out[(long)row * N + col] = v;
                }
            }
        }
    }
}

// ---------- flash attention: 128 q-rows/block, KVBLK=128 (half the tiles), 2 blocks/CU ----------
__launch_bounds__(256, 2)
__global__ void attn_kernel(const short* __restrict__ qrole, const short* __restrict__ krole,
                            const short* __restrict__ vT, short* __restrict__ y) {
    __shared__ __align__(16) short K_lds[2][128][64];   // [buf][j][d]   32 KB
    __shared__ __align__(16) short V_lds[2][64][128];   // [buf][d][j']  32 KB
    __shared__ __align__(16) short P_lds[4][16][128];   // [wave][q][j'] 16 KB
    const int tid = threadIdx.x, lane = tid & 63, w = tid >> 6;
    const int r16 = lane & 15, g = lane >> 4;
    const int idb = blockIdx.x;
    const int bh = idb & 63;           // id%8 == bh%8 -> one XCD per bh (KV L2-resident)
    const int c = 15 - ((idb >> 6) & 15);  // global LPT: descending T
    const int q0 = c << 7;
    const int T = c + 1;               // KVBLK=128 -> c+1 tiles
    const short* qb = qrole + (long)bh * (2048 * 64);
    const char* kbyte = (const char*)(krole + (long)bh * (2048 * 64));
    const char* vbyte = (const char*)(vT + (long)bh * (64 * 2048));
    const int b = bh >> 4, h = bh & 15;

    bf16x8 qf[2][2];
    #pragma unroll
    for (int m = 0; m < 2; ++m)
        #pragma unroll
        for (int ks = 0; ks < 2; ++ks)
            qf[m][ks] = *(const bf16x8*)&qb[(long)(q0 + m * 64 + w * 16 + r16) * 64 + ks * 32 + g * 8];

    f32x4 o[2][4] = {};
    float mr[2], lr[2];
    #pragma unroll
    for (int m = 0; m < 2; ++m) { mr[m] = -1e30f; lr[m] = 0.f; }

    // staging pointers: K tile = 16 KB linear; V tile = 64 d-rows x 256 B
    const char* kgp = kbyte + (long)tid * 16;                         // + t*16384 + it*4096
    const char* vgp = vbyte + (tid >> 4) * 4096 + (tid & 15) * 16;    // + t*256 + it*65536
    char* Kb_ = (char*)&K_lds[0][0][0];
    char* Vb_ = (char*)&V_lds[0][0][0];

    // stage tile 0 into buf 0
    #pragma unroll
    for (int it = 0; it < 4; ++it) {
        gload_lds16(kgp + it * 4096, Kb_ + tid * 16 + it * 4096);
        gload_lds16(vgp + (long)it * 65536, Vb_ + tid * 16 + it * 4096);
    }

    const int psw = (r16 & 7) << 4;
    char* prow = (char*)&P_lds[w][r16][0];

    for (int t = 0; t < T; ++t) {
        __syncthreads();               // stage(t) landed (vmcnt drain) + all waves synced
        const int cur = t & 1;
        if (t + 1 < T) {               // issue stage(t+1): hidden under compute(t)
            const char* ksrc = kgp + (long)(t + 1) * 16384;
            const char* vsrc = vgp + (long)(t + 1) * 256;
            char* kdst = Kb_ + (cur ^ 1) * 16384;
            char* vdst = Vb_ + (cur ^ 1) * 16384;
            #pragma unroll
            for (int it = 0; it < 4; ++it) {
                gload_lds16(ksrc + it * 4096, kdst + tid * 16 + it * 4096);
                gload_lds16(vsrc + (long)it * 65536, vdst + tid * 16 + it * 4096);
            }
        }
        const int jt = t << 7;
        const char* kbase = Kb_ + cur * 16384;
        const char* vbase = Vb_ + cur * 16384;
        const bool diag = (t == T - 1);

        #pragma unroll
        for (int m = 0; m < 2; ++m) {
            const int qbase = q0 + m * 64 + w * 16;

            // S^T = K * Q (exp2 domain), 8 n-frags over 128 j
            f32x4 s[8] = {};
            __builtin_amdgcn_s_setprio(1);
            #pragma unroll
            for (int ks = 0; ks < 2; ++ks)
                #pragma unroll
                for (int n = 0; n < 8; ++n) {
                    bf16x8 kf = *(const bf16x8*)(kbase + (n * 16 + r16) * 128 + ((ks * 64 + g * 16) ^ psw));
                    s[n] = __builtin_amdgcn_mfma_f32_16x16x32_bf16(kf, qf[m][ks], s[n], 0, 0, 0);
                }
            __builtin_amdgcn_s_setprio(0);
            if (diag) {                  // final tile: mask j > i (covers m=0's fully-dead upper half too)
                const int i = qbase + r16;
                #pragma unroll
                for (int n = 0; n < 8; ++n)
                    #pragma unroll
                    for (int r = 0; r < 4; ++r)
                        if (jt + n * 16 + g * 4 + r > i) s[n][r] = -1e30f;
            }
            // row max over 32 values: per-n max3 pairs then tree
            float tn[8];
            #pragma unroll
            for (int n = 0; n < 8; ++n)
                tn[n] = fmaxf(fmaxf(s[n][0], s[n][1]), fmaxf(s[n][2], s[n][3]));
            float u0 = fmaxf(fmaxf(tn[0], tn[1]), fmaxf(tn[2], tn[3]));
            float u1 = fmaxf(fmaxf(tn[4], tn[5]), fmaxf(tn[6], tn[7]));
            float tm = fmaxf(u0, u1);
            tm = fmaxf(tm, __shfl_xor(tm, 16));
            tm = fmaxf(tm, __shfl_xor(tm, 32));
            // defer-max (T13), log2 units (11.5 ~= 8 nats)
            if (__any(tm > mr[m] + 11.5f)) {
                float mn = fmaxf(mr[m], tm);
                float sc = fexp2(mr[m] - mn);
                mr[m] = mn;
                lr[m] *= sc;
                float scr[4];
                #pragma unroll
                for (int r = 0; r < 4; ++r) scr[r] = __shfl(sc, (g << 2) + r);
                #pragma unroll
                for (int nd = 0; nd < 4; ++nd)
                    #pragma unroll
                    for (int r = 0; r < 4; ++r)
                        o[m][nd][r] *= scr[r];
            }
            // p = exp2(s - m) via packed subtract, cvt_pk pack -> swizzled P_lds
            const float nm = -mr[m];
            f32x2 nm2; nm2.x = nm; nm2.y = nm;
            float lsum = 0.f;
            #pragma unroll
            for (int n = 0; n < 8; ++n) {
                f32x2 lo; lo.x = s[n][0]; lo.y = s[n][1];
                f32x2 hi; hi.x = s[n][2]; hi.y = s[n][3];
                f32x2 e01 = pk_add(lo, nm2);
                f32x2 e23 = pk_add(hi, nm2);
                float p0 = fexp2(e01.x);
                float p1 = fexp2(e01.y);
                float p2 = fexp2(e23.x);
                float p3 = fexp2(e23.y);
                unsigned w0 = cvt_pk_bf16(p0, p1);
                unsigned w1 = cvt_pk_bf16(p2, p3);
                unsigned long long dw = ((unsigned long long)w1 << 32) | w0;
                *(unsigned long long*)(prow + ((n * 32 + g * 8) ^ psw)) = dw;
                lsum += (p0 + p1) + (p2 + p3);
            }
            lsum += __shfl_xor(lsum, 16);
            lsum += __shfl_xor(lsum, 32);
            lr[m] += lsum;
            // PV: 4 K=32 slices over 128 j
            __builtin_amdgcn_s_setprio(1);
            #pragma unroll
            for (int ks = 0; ks < 4; ++ks) {
                bf16x8 pf = *(const bf16x8*)(prow + ((ks * 64 + g * 16) ^ psw));
                #pragma unroll
                for (int nd = 0; nd < 4; ++nd) {
                    bf16x8 vf = *(const bf16x8*)(vbase + (nd * 16 + r16) * 256 + ((ks * 64 + g * 16) ^ psw));
                    o[m][nd] = __builtin_amdgcn_mfma_f32_16x16x32_bf16(pf, vf, o[m][nd], 0, 0, 0);
                }
            }
            __builtin_amdgcn_s_setprio(0);
        }
    }
    // epilogue: write y with GEMM2's k-chunk pre-swizzle
    #pragma unroll
    for (int m = 0; m < 2; ++m) {
        float inv[4];
        #pragma unroll
        for (int r = 0; r < 4; ++r) inv[r] = 1.0f / __shfl(lr[m], (g << 2) + r);
        const int li0 = q0 + m * 64 + w * 16 + (g << 2);
        #pragma unroll
        for (int nd = 0; nd < 4; ++nd)
            #pragma unroll
            for (int r = 0; r < 4; ++r) {
                int li = li0 + r;
                int sub = ((nd * 2 + (r16 >> 3)) ^ li) & 7;
                int kp = h * 64 + sub * 8 + (r16 & 7);
                y[(long)(b * 2048 + li) * 1024 + kp] = f2b(o[m][nd][r] * inv[r]);
            }
    }
}

extern "C" void kernel_launch(void* const* d_in, const int* in_sizes, int n_in,
                              void* d_out, int out_size, void* d_ws, size_t ws_size,
                              hipStream_t stream) {
    const float* x  = (const float*)d_in[0];
    const float* Wa = (const float*)d_in[1];
    const float* Wf = (const float*)d_in[2];
    float* out = (float*)d_out;
    char* ws = (char*)d_ws;
    short* xb  = (short*)(ws);                   // 16 MB (8192x1024 bf16, pre-swz); reused as y
    short* wab = (short*)(ws + (16l << 20));     // 6 MB  (3072x1024 bf16, T + pre-swz)
    short* wfb = (short*)(ws + (22l << 20));     // 2 MB  (1024x1024 bf16, T + pre-swz)
    short* qr  = (short*)(ws + (24l << 20));     // 16 MB [B,H,L,64] (pre-scaled by log2e/8)
    short* kr  = (short*)(ws + (40l << 20));     // 16 MB [B,H,L,64] (d-swizzled)
    short* vt  = (short*)(ws + (56l << 20));     // 16 MB [B,H,64,L] (j-swizzled per 64-tile)
    short* vrow = (short*)(ws + (72l << 20));    // 16 MB [B,H,L,64] row-major V staging

    conv_swz<<<2048, 256, 0, stream>>>(x, xb, (long)8192 * 128);
    transpose_swz<<<dim3(96, 32), dim3(32, 8), 0, stream>>>(Wa, wab, 1024, 3072);
    transpose_swz<<<dim3(32, 32), dim3(32, 8), 0, stream>>>(Wf, wfb, 1024, 1024);
    if (ws_size >= (89ull << 20)) {
        gemm_nt<2><<<dim3(24, 64), 256, 0, stream>>>(xb, wab, 8192, 3072, 1024, qr, kr, vrow, nullptr);
        vtrans_swz<<<2048, 256, 0, stream>>>(vrow, vt);
    } else {
        gemm_nt<0><<<dim3(24, 64), 256, 0, stream>>>(xb, wab, 8192, 3072, 1024, qr, kr, vt, nullptr);
    }
    attn_kernel<<<1024, 256, 0, stream>>>(qr, kr, vt, xb);
    gemm_nt<1><<<dim3(8, 64), 256, 0, stream>>>(xb, wfb, 8192, 1024, 1024, nullptr, nullptr, nullptr, out);
}

// Round 17
// 166.500 us; speedup vs baseline: 2.0802x; 1.0133x over previous
//
#include <hip/hip_runtime.h>
#include <hip/hip_bf16.h>

typedef __attribute__((ext_vector_type(8))) short bf16x8;
typedef __attribute__((ext_vector_type(4))) float f32x4;
typedef __attribute__((ext_vector_type(2))) float f32x2;

__device__ __forceinline__ short f2b(float f) {
    unsigned u = __builtin_bit_cast(unsigned, f);
    unsigned r = (u + 0x7FFFu + ((u >> 16) & 1u)) >> 16;
    return (short)r;
}

__device__ __forceinline__ unsigned cvt_pk_bf16(float lo, float hi) {
    unsigned r;
    asm("v_cvt_pk_bf16_f32 %0, %1, %2" : "=v"(r) : "v"(lo), "v"(hi));
    return r;
}

__device__ __forceinline__ float fexp2(float x) {
    float r;
    asm("v_exp_f32 %0, %1" : "=v"(r) : "v"(x));
    return r;
}

__device__ __forceinline__ f32x2 pk_add(f32x2 a, f32x2 b) {
    f32x2 d;
    asm("v_pk_add_f32 %0, %1, %2" : "=v"(d) : "v"(a), "v"(b));
    return d;
}

__device__ __forceinline__ void gload_lds16(const void* g, void* l) {
    __builtin_amdgcn_global_load_lds((const __attribute__((address_space(1))) unsigned*)g,
                                     (__attribute__((address_space(3))) unsigned*)l, 16, 0, 0);
}

// ---------- convert x f32->bf16, k-chunk pre-swizzled (chunk^row&7 within 64-group) ----------
__global__ void conv_swz(const float* __restrict__ in, short* __restrict__ out, long nch) {
    long i = (long)blockIdx.x * blockDim.x + threadIdx.x;
    long stride = (long)gridDim.x * blockDim.x;
    for (; i < nch; i += stride) {
        long m = i >> 7;            // row (K=1024 -> 128 chunks of 8)
        int ch = (int)(i & 127);
        int p = (ch & ~7) | ((ch ^ (int)m) & 7);
        const float4* s = (const float4*)(in + i * 8);
        float4 a = s[0], b = s[1];
        bf16x8 ov;
        ov[0] = f2b(a.x); ov[1] = f2b(a.y); ov[2] = f2b(a.z); ov[3] = f2b(a.w);
        ov[4] = f2b(b.x); ov[5] = f2b(b.y); ov[6] = f2b(b.z); ov[7] = f2b(b.w);
        *(bf16x8*)(out + (m << 10) + p * 8) = ov;
    }
}

// ---------- transpose + convert + k-chunk pre-swizzle: in [R=K][C] f32 -> outT [C][K] bf16 ----------
__global__ void transpose_swz(const float* __restrict__ in, short* __restrict__ outT, int R, int C) {
    __shared__ float t[32][33];
    int c0 = blockIdx.x * 32, r0 = blockIdx.y * 32;
    int tx = threadIdx.x, ty = threadIdx.y; // 32 x 8
    #pragma unroll
    for (int j = 0; j < 4; ++j)
        t[ty + j * 8][tx] = in[(long)(r0 + ty + j * 8) * C + c0 + tx];
    __syncthreads();
    #pragma unroll
    for (int j = 0; j < 4; ++j) {
        int n = c0 + ty + j * 8;    // output row
        int k = r0 + tx;            // k index
        int kp = (k & ~63) | ((((k >> 3) ^ n) & 7) << 3) | (k & 7);
        outT[(long)n * R + kp] = f2b(t[tx][ty + j * 8]);
    }
}

// ---------- v transpose: vrow [bh][li][64] -> vT [bh][64][2048] with j-swizzle ----------
__global__ void vtrans_swz(const short* __restrict__ vrow, short* __restrict__ vT) {
    __shared__ short t[64][66];
    const int bh = blockIdx.x & 63;
    const int li0 = ((blockIdx.x >> 6) & 31) << 6;
    const int tid = threadIdx.x;
    const short* src = vrow + ((long)bh * 2048 + li0) * 64;
    {
        int id0 = tid, id1 = tid + 256;      // 512 16B-chunks: 64 rows x 8 chunks
        int r0 = id0 >> 3, c0 = id0 & 7;
        int r1 = id1 >> 3, c1 = id1 & 7;
        *(bf16x8*)&t[r0][c0 * 8] = *(const bf16x8*)&src[r0 * 64 + c0 * 8];
        *(bf16x8*)&t[r1][c1 * 8] = *(const bf16x8*)&src[r1 * 64 + c1 * 8];
    }
    __syncthreads();
    const int d = tid >> 2, part = tid & 3;  // each thread: row d, li-chunks 2*part, 2*part+1
    short* dst = vT + ((long)bh * 64 + d) * 2048 + li0;
    const int sw = d & 7;
    #pragma unroll
    for (int cc = 0; cc < 2; ++cc) {
        int cl = part * 2 + cc;              // source li-chunk (8 elems)
        bf16x8 val;
        #pragma unroll
        for (int i = 0; i < 8; ++i) val[i] = t[cl * 8 + i][d];
        *(bf16x8*)&dst[(cl ^ sw) * 8] = val;
    }
}

// ---------- NT GEMM, m97 structure: BK=64, global_load_lds, swizzled ds_read ----------
// MODE 0: scatter epilogue with direct vT column write (fallback).
// MODE 2: scatter epilogue with row-major vrow (coalesced; vtrans_swz finishes).
// MODE 1: plain f32 out (GEMM2).
template<int MODE>
__launch_bounds__(256, 4)
__global__ void gemm_nt(const short* __restrict__ A, const short* __restrict__ Bt,
                        int M, int N, int K,
                        short* __restrict__ qrole, short* __restrict__ krole,
                        short* __restrict__ vT, float* __restrict__ out) {
    __shared__ __align__(16) short As[128][64];
    __shared__ __align__(16) short Bs[128][64];
    const int tid = threadIdx.x;
    const int lane = tid & 63;
    const int wid = tid >> 6;
    const int wm = wid >> 1, wn = wid & 1;
    const int m0 = blockIdx.y * 128, n0 = blockIdx.x * 128;
    const int r16 = lane & 15, g = lane >> 4;
    const int sw = r16 & 7;
    const char* Ab = (const char*)A;
    const char* Bb = (const char*)Bt;
    const long Kb = (long)K * 2;
    f32x4 acc[4][4] = {};
    for (int k0 = 0; k0 < K; k0 += 64) {
        #pragma unroll
        for (int it = 0; it < 4; ++it) {
            int id = it * 256 + tid;      // 0..1023 chunk ids
            int r = id >> 3, cch = id & 7;
            gload_lds16(Ab + (long)(m0 + r) * Kb + k0 * 2 + cch * 16, (char*)As + id * 16);
            gload_lds16(Bb + (long)(n0 + r) * Kb + k0 * 2 + cch * 16, (char*)Bs + id * 16);
        }
        __syncthreads();
        #pragma unroll
        for (int kk = 0; kk < 2; ++kk) {
            bf16x8 af[4], bfr[4];
            #pragma unroll
            for (int m = 0; m < 4; ++m)
                af[m] = *(const bf16x8*)&As[wm * 64 + m * 16 + r16][((kk * 4 + g) ^ sw) * 8];
            #pragma unroll
            for (int n = 0; n < 4; ++n)
                bfr[n] = *(const bf16x8*)&Bs[wn * 64 + n * 16 + r16][((kk * 4 + g) ^ sw) * 8];
            #pragma unroll
            for (int m = 0; m < 4; ++m)
                #pragma unroll
                for (int n = 0; n < 4; ++n)
                    acc[m][n] = __builtin_amdgcn_mfma_f32_16x16x32_bf16(af[m], bfr[n], acc[m][n], 0, 0, 0);
        }
        __syncthreads();
    }
    #pragma unroll
    for (int m = 0; m < 4; ++m) {
        #pragma unroll
        for (int n = 0; n < 4; ++n) {
            #pragma unroll
            for (int r = 0; r < 4; ++r) {
                int row = m0 + wm * 64 + m * 16 + g * 4 + r;
                int col = n0 + wn * 64 + n * 16 + r16;
                float v = acc[m][n][r];
                if (MODE != 1) {
                    int which = col >> 10, cc = col & 1023;
                    int h = cc >> 6, d = cc & 63;
                    int b = row >> 11, li = row & 2047;
                    int bh = b * 16 + h;
                    // q pre-scaled by (1/8)*log2(e) -> softmax runs in exp2 domain
                    if (which == 0)      qrole[((long)bh * 2048 + li) * 64 + d] = f2b(v * 0.18033688f);
                    else if (which == 1) krole[((long)bh * 2048 + li) * 64 + (d ^ ((li & 7) << 3))] = f2b(v);
                    else if (MODE == 2)  vT[((long)bh * 2048 + li) * 64 + d] = f2b(v);   // vrow, coalesced
                    else                 vT[((long)bh * 64 + d) * 2048 + ((li & ~63) | ((li & 63) ^ ((d & 7) << 3)))] = f2b(v);
                } else {
                    out[(long)row * N + col] = v;
                }
            }
        }
    }
}

// ---------- flash attention: 128 q-rows/block, KVBLK=128, no steady-state cross-lane ops ----------
__launch_bounds__(256, 2)
__global__ void attn_kernel(const short* __restrict__ qrole, const short* __restrict__ krole,
                            const short* __restrict__ vT, short* __restrict__ y) {
    __shared__ __align__(16) short K_lds[2][128][64];   // [buf][j][d]   32 KB
    __shared__ __align__(16) short V_lds[2][64][128];   // [buf][d][j']  32 KB
    __shared__ __align__(16) short P_lds[4][16][128];   // [wave][q][j'] 16 KB
    const int tid = threadIdx.x, lane = tid & 63, w = tid >> 6;
    const int r16 = lane & 15, g = lane >> 4;
    const int idb = blockIdx.x;
    const int bh = idb & 63;           // id%8 == bh%8 -> one XCD per bh (KV L2-resident)
    const int c = 15 - ((idb >> 6) & 15);  // global LPT: descending T
    const int q0 = c << 7;
    const int T = c + 1;               // KVBLK=128 -> c+1 tiles
    const short* qb = qrole + (long)bh * (2048 * 64);
    const char* kbyte = (const char*)(krole + (long)bh * (2048 * 64));
    const char* vbyte = (const char*)(vT + (long)bh * (64 * 2048));
    const int b = bh >> 4, h = bh & 15;

    bf16x8 qf[2][2];
    #pragma unroll
    for (int m = 0; m < 2; ++m)
        #pragma unroll
        for (int ks = 0; ks < 2; ++ks)
            qf[m][ks] = *(const bf16x8*)&qb[(long)(q0 + m * 64 + w * 16 + r16) * 64 + ks * 32 + g * 8];

    f32x4 o[2][4] = {};
    float mr[2], lr[2];                // lr = per-lane PARTIAL sum (reduced in epilogue)
    #pragma unroll
    for (int m = 0; m < 2; ++m) { mr[m] = -1e30f; lr[m] = 0.f; }

    // staging pointers: K tile = 16 KB linear; V tile = 64 d-rows x 256 B
    const char* kgp = kbyte + (long)tid * 16;                         // + t*16384 + it*4096
    const char* vgp = vbyte + (tid >> 4) * 4096 + (tid & 15) * 16;    // + t*256 + it*65536
    char* Kb_ = (char*)&K_lds[0][0][0];
    char* Vb_ = (char*)&V_lds[0][0][0];

    // stage tile 0 into buf 0
    #pragma unroll
    for (int it = 0; it < 4; ++it) {
        gload_lds16(kgp + it * 4096, Kb_ + tid * 16 + it * 4096);
        gload_lds16(vgp + (long)it * 65536, Vb_ + tid * 16 + it * 4096);
    }

    const int psw = (r16 & 7) << 4;
    char* prow = (char*)&P_lds[w][r16][0];

    for (int t = 0; t < T; ++t) {
        __syncthreads();               // stage(t) landed (vmcnt drain) + all waves synced
        const int cur = t & 1;
        if (t + 1 < T) {               // issue stage(t+1): hidden under compute(t)
            const char* ksrc = kgp + (long)(t + 1) * 16384;
            const char* vsrc = vgp + (long)(t + 1) * 256;
            char* kdst = Kb_ + (cur ^ 1) * 16384;
            char* vdst = Vb_ + (cur ^ 1) * 16384;
            #pragma unroll
            for (int it = 0; it < 4; ++it) {
                gload_lds16(ksrc + it * 4096, kdst + tid * 16 + it * 4096);
                gload_lds16(vsrc + (long)it * 65536, vdst + tid * 16 + it * 4096);
            }
        }
        const int jt = t << 7;
        const char* kbase = Kb_ + cur * 16384;
        const char* vbase = Vb_ + cur * 16384;
        const bool diag = (t == T - 1);

        #pragma unroll
        for (int m = 0; m < 2; ++m) {
            const int qbase = q0 + m * 64 + w * 16;

            // S^T = K * Q (exp2 domain), 8 n-frags over 128 j
            f32x4 s[8] = {};
            __builtin_amdgcn_s_setprio(1);
            #pragma unroll
            for (int ks = 0; ks < 2; ++ks)
                #pragma unroll
                for (int n = 0; n < 8; ++n) {
                    bf16x8 kf = *(const bf16x8*)(kbase + (n * 16 + r16) * 128 + ((ks * 64 + g * 16) ^ psw));
                    s[n] = __builtin_amdgcn_mfma_f32_16x16x32_bf16(kf, qf[m][ks], s[n], 0, 0, 0);
                }
            __builtin_amdgcn_s_setprio(0);
            if (diag) {                  // final tile: mask j > i
                const int i = qbase + r16;
                #pragma unroll
                for (int n = 0; n < 8; ++n)
                    #pragma unroll
                    for (int r = 0; r < 4; ++r)
                        if (jt + n * 16 + g * 4 + r > i) s[n][r] = -1e30f;
            }
            // per-lane max only (cross-lane reduce moved inside the rare rescale branch;
            // __any ballot sees the threshold crossing on per-lane partials exactly as well)
            float tn[8];
            #pragma unroll
            for (int n = 0; n < 8; ++n)
                tn[n] = fmaxf(fmaxf(s[n][0], s[n][1]), fmaxf(s[n][2], s[n][3]));
            float u0 = fmaxf(fmaxf(tn[0], tn[1]), fmaxf(tn[2], tn[3]));
            float u1 = fmaxf(fmaxf(tn[4], tn[5]), fmaxf(tn[6], tn[7]));
            float tm = fmaxf(u0, u1);
            // defer-max (T13), log2 units (11.5 ~= 8 nats)
            if (__any(tm > mr[m] + 11.5f)) {
                tm = fmaxf(tm, __shfl_xor(tm, 16));   // true row max (rare path only)
                tm = fmaxf(tm, __shfl_xor(tm, 32));
                float mn = fmaxf(mr[m], tm);
                float sc = fexp2(mr[m] - mn);   // uniform across g-group -> scales partials exactly
                mr[m] = mn;
                lr[m] *= sc;
                float scr[4];
                #pragma unroll
                for (int r = 0; r < 4; ++r) scr[r] = __shfl(sc, (g << 2) + r);
                #pragma unroll
                for (int nd = 0; nd < 4; ++nd)
                    #pragma unroll
                    for (int r = 0; r < 4; ++r)
                        o[m][nd][r] *= scr[r];
            }
            // p = exp2(s - m) via packed subtract, cvt_pk pack -> swizzled P_lds
            const float nm = -mr[m];
            f32x2 nm2; nm2.x = nm; nm2.y = nm;
            float lsum = 0.f;
            #pragma unroll
            for (int n = 0; n < 8; ++n) {
                f32x2 lo; lo.x = s[n][0]; lo.y = s[n][1];
                f32x2 hi; hi.x = s[n][2]; hi.y = s[n][3];
                f32x2 e01 = pk_add(lo, nm2);
                f32x2 e23 = pk_add(hi, nm2);
                float p0 = fexp2(e01.x);
                float p1 = fexp2(e01.y);
                float p2 = fexp2(e23.x);
                float p3 = fexp2(e23.y);
                unsigned w0 = cvt_pk_bf16(p0, p1);
                unsigned w1 = cvt_pk_bf16(p2, p3);
                unsigned long long dw = ((unsigned long long)w1 << 32) | w0;
                *(unsigned long long*)(prow + ((n * 32 + g * 8) ^ psw)) = dw;
                lsum += (p0 + p1) + (p2 + p3);
            }
            lr[m] += lsum;               // per-lane partial (cross-lane deferred to epilogue)
            // PV: 4 K=32 slices over 128 j
            __builtin_amdgcn_s_setprio(1);
            #pragma unroll
            for (int ks = 0; ks < 4; ++ks) {
                bf16x8 pf = *(const bf16x8*)(prow + ((ks * 64 + g * 16) ^ psw));
                #pragma unroll
                for (int nd = 0; nd < 4; ++nd) {
                    bf16x8 vf = *(const bf16x8*)(vbase + (nd * 16 + r16) * 256 + ((ks * 64 + g * 16) ^ psw));
                    o[m][nd] = __builtin_amdgcn_mfma_f32_16x16x32_bf16(pf, vf, o[m][nd], 0, 0, 0);
                }
            }
            __builtin_amdgcn_s_setprio(0);
        }
    }
    // epilogue: reduce partial lr across g-group, then write y with GEMM2's k-chunk pre-swizzle
    #pragma unroll
    for (int m = 0; m < 2; ++m) {
        lr[m] += __shfl_xor(lr[m], 16);
        lr[m] += __shfl_xor(lr[m], 32);
        float inv[4];
        #pragma unroll
        for (int r = 0; r < 4; ++r) inv[r] = 1.0f / __shfl(lr[m], (g << 2) + r);
        const int li0 = q0 + m * 64 + w * 16 + (g << 2);
        #pragma unroll
        for (int nd = 0; nd < 4; ++nd)
            #pragma unroll
            for (int r = 0; r < 4; ++r) {
                int li = li0 + r;
                int sub = ((nd * 2 + (r16 >> 3)) ^ li) & 7;
                int kp = h * 64 + sub * 8 + (r16 & 7);
                y[(long)(b * 2048 + li) * 1024 + kp] = f2b(o[m][nd][r] * inv[r]);
            }
    }
}

extern "C" void kernel_launch(void* const* d_in, const int* in_sizes, int n_in,
                              void* d_out, int out_size, void* d_ws, size_t ws_size,
                              hipStream_t stream) {
    const float* x  = (const float*)d_in[0];
    const float* Wa = (const float*)d_in[1];
    const float* Wf = (const float*)d_in[2];
    float* out = (float*)d_out;
    char* ws = (char*)d_ws;
    short* xb  = (short*)(ws);                   // 16 MB (8192x1024 bf16, pre-swz); reused as y
    short* wab = (short*)(ws + (16l << 20));     // 6 MB  (3072x1024 bf16, T + pre-swz)
    short* wfb = (short*)(ws + (22l << 20));     // 2 MB  (1024x1024 bf16, T + pre-swz)
    short* qr  = (short*)(ws + (24l << 20));     // 16 MB [B,H,L,64] (pre-scaled by log2e/8)
    short* kr  = (short*)(ws + (40l << 20));     // 16 MB [B,H,L,64] (d-swizzled)
    short* vt  = (short*)(ws + (56l << 20));     // 16 MB [B,H,64,L] (j-swizzled per 64-tile)
    short* vrow = (short*)(ws + (72l << 20));    // 16 MB [B,H,L,64] row-major V staging

    conv_swz<<<2048, 256, 0, stream>>>(x, xb, (long)8192 * 128);
    transpose_swz<<<dim3(96, 32), dim3(32, 8), 0, stream>>>(Wa, wab, 1024, 3072);
    transpose_swz<<<dim3(32, 32), dim3(32, 8), 0, stream>>>(Wf, wfb, 1024, 1024);
    if (ws_size >= (89ull << 20)) {
        gemm_nt<2><<<dim3(24, 64), 256, 0, stream>>>(xb, wab, 8192, 3072, 1024, qr, kr, vrow, nullptr);
        vtrans_swz<<<2048, 256, 0, stream>>>(vrow, vt);
    } else {
        gemm_nt<0><<<dim3(24, 64), 256, 0, stream>>>(xb, wab, 8192, 3072, 1024, qr, kr, vt, nullptr);
    }
    attn_kernel<<<1024, 256, 0, stream>>>(qr, kr, vt, xb);
    gemm_nt<1><<<dim3(8, 64), 256, 0, stream>>>(xb, wfb, 8192, 1024, 1024, nullptr, nullptr, nullptr, out);
}